// Round 7
// baseline (32680.353 us; speedup 1.0000x reference)
//
#include <hip/hip_runtime.h>
#include <math.h>

#define T_STEPS 16384
#define IN_DIM  14
#define H_DIM   100
#define G_DIM   300   // 3*H

// float offsets inside each 1024-float LDS buffer AND each 256-float global mirror
#define H1OFF 0      // h1[0..100)
#define H2OFF 128    // h2[0..100)
#define AOFF  256    // a (layer-1 input preacts) [0..300)  (LDS only)

typedef float f2 __attribute__((ext_vector_type(2)));

#define REP25(M) M(0) M(1) M(2) M(3) M(4) M(5) M(6) M(7) M(8) M(9) M(10) M(11) \
                 M(12) M(13) M(14) M(15) M(16) M(17) M(18) M(19) M(20) M(21) M(22) M(23) M(24)

// ---------------- Phase 0: gi0[t][j] = b_ih0[j] + sum_k x[t][k]*w_ih0[j][k] ----------------
__global__ void gi0_kernel(const float* __restrict__ x,
                           const float* __restrict__ w_ih0,
                           const float* __restrict__ b_ih0,
                           float* __restrict__ gi0) {
    int e = blockIdx.x * blockDim.x + threadIdx.x;
    if (e >= T_STEPS * G_DIM) return;
    int t = e / G_DIM;
    int j = e - t * G_DIM;
    const float* xr = x + t * IN_DIM;
    const float* wr = w_ih0 + j * IN_DIM;
    float acc = b_ih0[j];
    #pragma unroll
    for (int k = 0; k < IN_DIM; ++k) acc = fmaf(xr[k], wr[k], acc);
    gi0[e] = acc;
}

// ---------------- Phase 1: persistent single-workgroup sequential GRU ----------------
// ROUND 7. Seven-round fit: step time tracks the number of ds_read_b128
// WAVE-INSTRUCTIONS (~11-12 cyc each on the CU's single DS pipe, broadcast or
// not): R1=200 reads~2300cyc, R3=375~3300, R6=250~2770. The h-vector
// broadcast (8 waves x 25 b128 per step) IS the bottleneck; cross-CU
// pipelining (R4/R5/R6) never beat R1. Fix: keep R1's structure (best, 15.5
// ms) but move the h broadcast to the VMEM pipe -- h1/h2 mirrored in a tiny
// global scratch (L2/vL1-resident), dot phase reads it via
// global_load_dwordx4. Same-CU RAW through L2 is safe: vL1 is write-through
// + line-invalidating, and __syncthreads drains vmcnt before the barrier.
// LDS keeps per-lane-scalar traffic only (h_old, a-slab, bpermutes).
// Lane mapping, FMA chains, reduce order, gate math VERBATIM from R1 ->
// absmax 0.0 preserved. Weight rows stay 100 named f2 SSA values per lane
// (arrays would hit scratch; partial AGPR residency accepted -- VALU ~1340
// cyc/step is the predicted new bound).
__global__ __launch_bounds__(512, 2)
void gru_seq_kernel(const float* __restrict__ gi0,
                    const float* __restrict__ w_hh0,
                    const float* __restrict__ b_hh0,
                    const float* __restrict__ w_ih1,
                    const float* __restrict__ b_ih1,
                    const float* __restrict__ w_hh1,
                    const float* __restrict__ b_hh1,
                    const float* __restrict__ fc_w,
                    const float* __restrict__ fc_b,
                    float* __restrict__ out,
                    float* __restrict__ hg) {   // global h mirror: [2][256] floats, zeroed
    __shared__ __align__(16) float bufA[1024];
    __shared__ __align__(16) float bufB[1024];

    const int tid = threadIdx.x;
    const int wv = tid >> 6;
    const int ln = tid & 63;
    const bool gateWave = (tid < 320);

    const float* pra; const float* prb; float bias0, bias1;
    int hbase4 = 0;      // float4 index of this lane's h vector (0 = h1, 32 = h2)
    bool isA = false;
    int gg = 0;          // global gate id for A-lanes (0..199)
    int jw = 0;          // write index (gate-local j, or l1in float2 slot)

    if (gateWave) {
        if (ln < 40) {                       // A-lane: r-row + z-row of gate gg
            isA = true;
            gg = wv * 40 + ln;
            int gl = (gg < 100) ? gg : gg - 100;
            const float* wm = (gg < 100) ? w_hh0 : w_hh1;
            const float* bm = (gg < 100) ? b_hh0 : b_hh1;
            pra = wm + (size_t)gl * H_DIM;            // r-row
            prb = wm + (size_t)(gl + 100) * H_DIM;    // z-row
            bias0 = bm[gl]; bias1 = bm[gl + 100];
            hbase4 = (gg < 100) ? (H1OFF / 4) : (H2OFF / 4);
            jw = gl;
        } else {                             // B-lane: n-rows of gates (pb, pb+1)
            int b = (ln < 60) ? (ln - 40) : 19;       // lanes 60-63 clone lane 59
            int pb = wv * 40 + 2 * b;
            int gl = (pb < 100) ? pb : pb - 100;
            const float* wm = (pb < 100) ? w_hh0 : w_hh1;
            const float* bm = (pb < 100) ? b_hh0 : b_hh1;
            pra = wm + (size_t)(200 + gl) * H_DIM;
            prb = wm + (size_t)(201 + gl) * H_DIM;
            bias0 = bm[200 + gl]; bias1 = bm[201 + gl];
            hbase4 = (pb < 100) ? (H1OFF / 4) : (H2OFF / 4);
        }
    } else {                                 // l1in: 2 rows of w_ih1
        int s = tid - 320;
        int q = (s < 150) ? s : 149;                  // tail lanes clone, never write
        pra = w_ih1 + (size_t)(2 * q) * H_DIM;
        prb = w_ih1 + (size_t)(2 * q + 1) * H_DIM;
        bias0 = b_ih1[2 * q]; bias1 = b_ih1[2 * q + 1];
        hbase4 = H1OFF / 4;
        jw = q;
    }
    const bool l1inActive = (!gateWave) && (tid - 320 < 150);
    const int hsoff = hbase4 << 2;           // scalar float offset of this lane's h

    // ---- weight registers: 100 named f2 values (200 VGPRs), guaranteed SSA ----
    #define DECLK(k) f2 w0a_##k, w0b_##k, w1a_##k, w1b_##k;
    REP25(DECLK)
    #undef DECLK
    {
        const float4* p0 = reinterpret_cast<const float4*>(pra);
        const float4* p1 = reinterpret_cast<const float4*>(prb);
        #define LOADK(k) { float4 A = p0[k]; w0a_##k.x = A.x; w0a_##k.y = A.y; w0b_##k.x = A.z; w0b_##k.y = A.w; \
                           float4 B = p1[k]; w1a_##k.x = B.x; w1a_##k.y = B.y; w1b_##k.x = B.z; w1b_##k.y = B.w; }
        REP25(LOADK)
        #undef LOADK
    }

    for (int k = tid; k < 1024; k += 512) { bufA[k] = 0.0f; bufB[k] = 0.0f; }
    __syncthreads();

    // T+2 iterations: l0 produces h1(it) for it<T; l1in produces a(it-1) for
    // 1<=it<=T; l1 gates produce h2(it-2) for it>=2. One barrier per iteration.
    for (int it = 0; it < T_STEPS + 2; ++it) {
        float* bc = (it & 1) ? bufB : bufA;   // LDS read buffer (written last iter)
        float* bn = (it & 1) ? bufA : bufB;   // LDS write buffer
        const float* hgc = hg + (it & 1) * 256;        // global h mirror, read side
        float*       hgn = hg + ((it & 1) ^ 1) * 256;  // global h mirror, write side

        // Prefetch gate inputs (global gi0 for l0, LDS a-slab for l1) + h_old.
        float gr = 0.f, gz = 0.f, gn = 0.f, hold = 0.f;
        if (isA) {
            if (gg < 100) {
                if (it < T_STEPS) {
                    const float* p = gi0 + (size_t)it * G_DIM + jw;
                    gr = p[0]; gz = p[H_DIM]; gn = p[2 * H_DIM];
                }
            } else {
                gr = bc[AOFF + jw];
                gz = bc[AOFF + 100 + jw];
                gn = bc[AOFF + 200 + jw];
            }
            hold = bc[hsoff + jw];
        }

        // Dot phase: 2 rows x 100, packed-f32 FMAs. Broadcast reads of h now
        // come from the GLOBAL mirror (VMEM pipe; vL1-hit after first touch)
        // instead of ds_read_b128 (the 7-round DS-pipe bottleneck).
        const float4* hb4 = reinterpret_cast<const float4*>(hgc) + hbase4;
        f2 acc0, acc1, acc2, acc3;
        acc0.x = bias0; acc0.y = 0.0f;
        acc1.x = 0.0f;  acc1.y = 0.0f;
        acc2.x = bias1; acc2.y = 0.0f;
        acc3.x = 0.0f;  acc3.y = 0.0f;
        #define DOTK(k) { float4 V = hb4[k]; \
                          f2 va, vb; va.x = V.x; va.y = V.y; vb.x = V.z; vb.y = V.w; \
                          acc0 += w0a_##k * va; acc1 += w0b_##k * vb; \
                          acc2 += w1a_##k * va; acc3 += w1b_##k * vb; }
        REP25(DOTK)
        #undef DOTK
        float d0 = (acc0.x + acc1.x) + (acc0.y + acc1.y);
        float d1 = (acc2.x + acc3.x) + (acc2.y + acc3.y);

        if (gateWave) {
            // B->A handoff of n-row dots: A-lane la pulls from B-lane 40+la/2,
            // parity selects which of B's two gates. Executed by ALL 64 lanes
            // (bpermute sources must be active).
            int src = (40 + (ln >> 1)) << 2;
            float nh0 = __int_as_float(__builtin_amdgcn_ds_bpermute(src, __float_as_int(d0)));
            float nh1 = __int_as_float(__builtin_amdgcn_ds_bpermute(src, __float_as_int(d1)));
            float nh = (ln & 1) ? nh1 : nh0;
            bool act = isA && ((gg < 100) ? (it < T_STEPS) : (it >= 2));
            if (act) {
                float r = 1.0f / (1.0f + expf(-(gr + d0)));
                float z = 1.0f / (1.0f + expf(-(gz + d1)));
                float n = tanhf(gn + r * nh);
                float hnew = (1.0f - z) * n + z * hold;
                bn[hsoff + jw] = hnew;        // LDS copy: h_old + FC epilogue
                hgn[hsoff + jw] = hnew;       // global mirror: next step's broadcast
            }
        } else if (l1inActive && it >= 1 && it <= T_STEPS) {
            reinterpret_cast<float2*>(bn + AOFF)[jw] = make_float2(d0, d1);
        }
        __syncthreads();   // compiler drains vmcnt(0) before s_barrier ->
                           // mirror stores visible (L2) before next step's loads
    }

    // FC epilogue: h2(T-1) was written at it = T+1 (odd since T is even)
    // -> landed in bufA. out = fc_b + fc_w . h2
    if (tid < 64) {
        float s = 0.0f;
        for (int j = tid; j < H_DIM; j += 64) s = fmaf(fc_w[j], bufA[H2OFF + j], s);
        #pragma unroll
        for (int off = 32; off > 0; off >>= 1) s += __shfl_down(s, off);
        if (tid == 0) out[0] = s + fc_b[0];
    }
}

extern "C" void kernel_launch(void* const* d_in, const int* in_sizes, int n_in,
                              void* d_out, int out_size, void* d_ws, size_t ws_size,
                              hipStream_t stream) {
    const float* x     = (const float*)d_in[0];
    const float* w_ih0 = (const float*)d_in[1];
    const float* w_hh0 = (const float*)d_in[2];
    const float* b_ih0 = (const float*)d_in[3];
    const float* b_hh0 = (const float*)d_in[4];
    const float* w_ih1 = (const float*)d_in[5];
    const float* w_hh1 = (const float*)d_in[6];
    const float* b_ih1 = (const float*)d_in[7];
    const float* b_hh1 = (const float*)d_in[8];
    const float* fc_w  = (const float*)d_in[9];
    const float* fc_b  = (const float*)d_in[10];
    float* out = (float*)d_out;

    float* gi0 = (float*)d_ws;                                   // 19.66 MB
    const size_t gi0_b = (size_t)T_STEPS * G_DIM * sizeof(float);
    float* hg = (float*)((char*)d_ws + gi0_b);                   // [2][256] floats
    hipMemsetAsync(hg, 0, 2 * 256 * sizeof(float), stream);      // h(0) = 0

    const int total = T_STEPS * G_DIM;
    gi0_kernel<<<(total + 255) / 256, 256, 0, stream>>>(x, w_ih0, b_ih0, gi0);
    gru_seq_kernel<<<1, 512, 0, stream>>>(gi0, w_hh0, b_hh0, w_ih1, b_ih1,
                                          w_hh1, b_hh1, fc_w, fc_b, out, hg);
}

// Round 8
// 21335.608 us; speedup vs baseline: 1.5317x; 1.5317x over previous
//
#include <hip/hip_runtime.h>
#include <math.h>

#define T_STEPS 16384
#define IN_DIM  14
#define H_DIM   100
#define G_DIM   300   // 3*H

typedef float f2 __attribute__((ext_vector_type(2)));
typedef float f4 __attribute__((ext_vector_type(4)));

#define REP25(M) M(0) M(1) M(2) M(3) M(4) M(5) M(6) M(7) M(8) M(9) M(10) M(11) \
                 M(12) M(13) M(14) M(15) M(16) M(17) M(18) M(19) M(20) M(21) M(22) M(23) M(24)

// ---------------- Phase 0: gi0[t][j] = b_ih0[j] + sum_k x[t][k]*w_ih0[j][k] ----------------
__global__ void gi0_kernel(const float* __restrict__ x,
                           const float* __restrict__ w_ih0,
                           const float* __restrict__ b_ih0,
                           float* __restrict__ gi0) {
    int e = blockIdx.x * blockDim.x + threadIdx.x;
    if (e >= T_STEPS * G_DIM) return;
    int t = e / G_DIM;
    int j = e - t * G_DIM;
    const float* xr = x + t * IN_DIM;
    const float* wr = w_ih0 + j * IN_DIM;
    float acc = b_ih0[j];
    #pragma unroll
    for (int k = 0; k < IN_DIM; ++k) acc = fmaf(xr[k], wr[k], acc);
    gi0[e] = acc;
}

// ---------------- Phase 1: three persistent workgroups, registers + LDS rings ----------------
// ROUND 8. Measured resource model (8 rounds): broadcast ds_read_b128 ~8 cyc
// on the CU's single DS pipe (R1 200 reads~2270cyc, R3 375~3090, R6 250~2770);
// VMEM broadcast of recurrent data is catastrophic (R7: serial L2 latency);
// AGPR-copy tax ~1.5 VALU/weight-float (allocator always demotes big per-lane
// arrays; accepted here). Design: split the 3 matrices across 3 blocks so
// each block issues only ~145 DS instrs/step, with NO atomics on gate waves:
//   B0: l0 recurrence, w_hh0 in regs (R3 5-wave gate layout, 1 row/lane:
//       waves 0-4, lanes 0-19 r / 20-39 z / 40-59 n of gates wave*20+ln%20;
//       bpermute combine). gi0 self-prefetch 1-ahead in regs. Wave 5
//       publishes h1(t-1) -> h1g global + release flag every 2 steps.
//   B1: a(t)=b_ih1+w_ih1.h1(t). Waves 0-4: 1 row/lane (300 rows), read h1
//       from an 8-slot LDS ring, store a -> ag global, per-wave release flag
//       every 2. Wave 5: stages h1(u+4) global->ring (flag-gated spin).
//   B2: l1 recurrence, w_hh1 in regs (same gate layout; gate inputs a(t)
//       read from an 8-slot LDS a-ring). Wave 5: stages a(k+4) -> ring. +FC.
// Streams cross CUs only in the laggable direction (B0->B1->B2); recurrent
// state never leaves its CU. Agent-scope atomics + wave-level release flags
// (vmcnt is per-wave -> lane0 release orders the wave's prior stores) --
// machinery proven in R6 (absmax 0.0). All dot chains / reduce order / gate
// math verbatim from R3/R6 -> bit-identical results.
__global__ __launch_bounds__(384, 2)
void gru3_kernel(const float* __restrict__ gi0,
                 const float* __restrict__ w_hh0, const float* __restrict__ b_hh0,
                 const float* __restrict__ w_ih1, const float* __restrict__ b_ih1,
                 const float* __restrict__ w_hh1, const float* __restrict__ b_hh1,
                 const float* __restrict__ fc_w,  const float* __restrict__ fc_b,
                 float* __restrict__ out,
                 float* __restrict__ h1g, float* __restrict__ ag, int* flags) {
    __shared__ __align__(16) float bufA[128];        // h double buffer (h1 in B0, h2 in B2)
    __shared__ __align__(16) float bufB[128];
    __shared__ __align__(16) float ring[8 * 304];    // B1: 8x128 h1 ring; B2: 8x304 a ring

    const int tid  = threadIdx.x;
    const int wave = tid >> 6;
    const int ln   = tid & 63;
    const int blk  = blockIdx.x;
    int* h1f = flags;                 // h1 steps published (B0 -> B1)
    int* af  = flags + 16;            // af + 8*w : a steps published by B1 wave w

    if (tid < 128) { bufA[tid] = 0.0f; bufB[tid] = 0.0f; }

    // gate-wave layout constants (waves 0-4 of B0/B2; R3-verified)
    const int ln20  = ln % 20;
    const int role  = ln / 20;                 // 0=r, 1=z, 2=n, 3=clone
    const int roleC = (role > 2) ? 2 : role;
    const bool isR  = (role == 0);
    const int q     = wave * 20 + ln20;        // gate id 0..99 (waves 0-4)
    const int adZ   = (20 + ln20) << 2;
    const int adN   = (40 + ln20) << 2;

    // ---- weight row: 50 named f2 values (100 f32) ----
    #define DECLK(k) f2 wa_##k, wb_##k;
    REP25(DECLK)
    #undef DECLK
    float bias = 0.0f;
    {
        const float* Wm; int row;
        if (blk == 0)      { Wm = w_hh0; row = roleC * 100 + q; if (wave < 5) bias = b_hh0[row]; }
        else if (blk == 1) { int rl = (ln < 60) ? ln : 59; Wm = w_ih1; row = wave * 60 + rl;
                             if (wave < 5) bias = b_ih1[row]; }
        else               { Wm = w_hh1; row = roleC * 100 + q; if (wave < 5) bias = b_hh1[row]; }
        if (wave >= 5) row = 0;   // helper waves: dummy row (never used)
        const f4* p_ = reinterpret_cast<const f4*>(Wm + (size_t)row * H_DIM);
        #define LOADK(k) { f4 V = p_[k]; wa_##k = V.lo; wb_##k = V.hi; }
        REP25(LOADK)
        #undef LOADK
    }
    // dot chain identical to R3/R6 (absmax 0.0): lo/hi f2 partials, same reduce
    #define DOTK(k) { f4 V = hb4_[k]; accA += wa_##k * V.lo; accB += wb_##k * V.hi; }

    if (blk == 0) {
        // =============== B0: layer-0 recurrence ===============
        float c_r = 0.f, c_z = 0.f, c_n = 0.f, n_r = 0.f, n_z = 0.f, n_n = 0.f;
        if (wave < 5 && isR) {                 // gi0(0)
            const float* p = gi0 + q;
            c_r = p[0]; c_z = p[H_DIM]; c_n = p[2 * H_DIM];
        }
        __syncthreads();

        for (int t = 0; t <= T_STEPS; ++t) {
            float* bc = (t & 1) ? bufB : bufA;
            float* bn = (t & 1) ? bufA : bufB;
            if (wave < 5) {
                if (isR && t + 1 < T_STEPS) {  // prefetch gi0(t+1), consumed next iter
                    const float* p = gi0 + (size_t)(t + 1) * G_DIM + q;
                    n_r = p[0]; n_z = p[H_DIM]; n_n = p[2 * H_DIM];
                }
                float hold = isR ? bc[q] : 0.f;
                const f4* hb4_ = reinterpret_cast<const f4*>(bc);
                f2 accA, accB;
                accA.x = bias; accA.y = 0.f; accB.x = 0.f; accB.y = 0.f;
                REP25(DOTK)
                float d  = (accA.x + accB.x) + (accA.y + accB.y);
                float dz = __int_as_float(__builtin_amdgcn_ds_bpermute(adZ, __float_as_int(d)));
                float dn = __int_as_float(__builtin_amdgcn_ds_bpermute(adN, __float_as_int(d)));
                if (isR && t < T_STEPS) {
                    float r = 1.0f / (1.0f + expf(-(c_r + d)));
                    float z = 1.0f / (1.0f + expf(-(c_z + dz)));
                    float n = tanhf(c_n + r * dn);
                    bn[q] = (1.0f - z) * n + z * hold;
                }
                c_r = n_r; c_z = n_z; c_n = n_n;
            } else if (wave == 5) {
                if (t >= 1) {                  // publish h1(t-1) (in bc)
                    float* dst = h1g + (size_t)(t - 1) * H_DIM;
                    __hip_atomic_store(dst + ln, bc[ln], __ATOMIC_RELAXED, __HIP_MEMORY_SCOPE_AGENT);
                    if (ln < 36)
                        __hip_atomic_store(dst + 64 + ln, bc[64 + ln], __ATOMIC_RELAXED, __HIP_MEMORY_SCOPE_AGENT);
                    if ((t & 1) == 0 && ln == 0)   // release orders this wave's stores (vmcnt per-wave)
                        __hip_atomic_store(h1f, t, __ATOMIC_RELEASE, __HIP_MEMORY_SCOPE_AGENT);
                }
            }
            __syncthreads();
        }
    } else if (blk == 1) {
        // =============== B1: a(t) = b_ih1 + w_ih1 . h1(t) ===============
        const int rl  = (ln < 60) ? ln : 59;
        const int row = wave * 60 + rl;
        int* myaf = af + wave * 8;
        int h1c = 0;

        if (wave == 5) {                       // prologue: stage h1(0..3)
            for (int e = 0; e < 4; ++e) {
                while (h1c < e + 1)
                    h1c = __hip_atomic_load(h1f, __ATOMIC_ACQUIRE, __HIP_MEMORY_SCOPE_AGENT);
                const float* src = h1g + (size_t)e * H_DIM;
                float* dst = ring + (e & 7) * 128;
                dst[ln] = __hip_atomic_load(src + ln, __ATOMIC_RELAXED, __HIP_MEMORY_SCOPE_AGENT);
                if (ln < 36)
                    dst[64 + ln] = __hip_atomic_load(src + 64 + ln, __ATOMIC_RELAXED, __HIP_MEMORY_SCOPE_AGENT);
            }
        }
        __syncthreads();

        for (int u = 0; u < T_STEPS; ++u) {
            if (wave < 5) {
                const f4* hb4_ = reinterpret_cast<const f4*>(ring + (u & 7) * 128);
                f2 accA, accB;
                accA.x = bias; accA.y = 0.f; accB.x = 0.f; accB.y = 0.f;
                REP25(DOTK)
                float d = (accA.x + accB.x) + (accA.y + accB.y);
                if (ln < 60)
                    __hip_atomic_store(ag + (size_t)u * G_DIM + row, d, __ATOMIC_RELAXED, __HIP_MEMORY_SCOPE_AGENT);
                if ((u & 1) == 1 && ln == 0)   // release orders this wave's a-stores
                    __hip_atomic_store(myaf, u + 1, __ATOMIC_RELEASE, __HIP_MEMORY_SCOPE_AGENT);
            } else if (wave == 5) {
                const int e = u + 4;           // stage h1(u+4) for iter u+4
                if (e < T_STEPS) {
                    while (h1c < e + 1)
                        h1c = __hip_atomic_load(h1f, __ATOMIC_ACQUIRE, __HIP_MEMORY_SCOPE_AGENT);
                    const float* src = h1g + (size_t)e * H_DIM;
                    float* dst = ring + (e & 7) * 128;
                    dst[ln] = __hip_atomic_load(src + ln, __ATOMIC_RELAXED, __HIP_MEMORY_SCOPE_AGENT);
                    if (ln < 36)
                        dst[64 + ln] = __hip_atomic_load(src + 64 + ln, __ATOMIC_RELAXED, __HIP_MEMORY_SCOPE_AGENT);
                }
            }
            __syncthreads();
        }
    } else {
        // =============== B2: layer-1 recurrence + FC ===============
        int am = 0;
        if (wave == 5) {                       // prologue: stage a(0..3)
            for (int e = 0; e < 4; ++e) {
                while (am < e + 1) {
                    int m0 = __hip_atomic_load(af +  0, __ATOMIC_ACQUIRE, __HIP_MEMORY_SCOPE_AGENT);
                    int m1 = __hip_atomic_load(af +  8, __ATOMIC_ACQUIRE, __HIP_MEMORY_SCOPE_AGENT);
                    int m2 = __hip_atomic_load(af + 16, __ATOMIC_ACQUIRE, __HIP_MEMORY_SCOPE_AGENT);
                    int m3 = __hip_atomic_load(af + 24, __ATOMIC_ACQUIRE, __HIP_MEMORY_SCOPE_AGENT);
                    int m4 = __hip_atomic_load(af + 32, __ATOMIC_ACQUIRE, __HIP_MEMORY_SCOPE_AGENT);
                    am = min(min(min(m0, m1), min(m2, m3)), m4);
                }
                const float* src = ag + (size_t)e * G_DIM;
                float* dst = ring + (e & 7) * 304;
                dst[ln]       = __hip_atomic_load(src + ln,       __ATOMIC_RELAXED, __HIP_MEMORY_SCOPE_AGENT);
                dst[64 + ln]  = __hip_atomic_load(src + 64 + ln,  __ATOMIC_RELAXED, __HIP_MEMORY_SCOPE_AGENT);
                dst[128 + ln] = __hip_atomic_load(src + 128 + ln, __ATOMIC_RELAXED, __HIP_MEMORY_SCOPE_AGENT);
                dst[192 + ln] = __hip_atomic_load(src + 192 + ln, __ATOMIC_RELAXED, __HIP_MEMORY_SCOPE_AGENT);
                if (ln < 44)
                    dst[256 + ln] = __hip_atomic_load(src + 256 + ln, __ATOMIC_RELAXED, __HIP_MEMORY_SCOPE_AGENT);
            }
        }
        __syncthreads();

        for (int k2 = 0; k2 < T_STEPS; ++k2) {
            float* bc = (k2 & 1) ? bufB : bufA;
            float* bn = (k2 & 1) ? bufA : bufB;
            if (wave < 5) {
                float g_r = 0.f, g_z = 0.f, g_n = 0.f, hold = 0.f;
                if (isR) {
                    const float* ap = ring + (k2 & 7) * 304;
                    g_r = ap[q]; g_z = ap[100 + q]; g_n = ap[200 + q];
                    hold = bc[q];
                }
                const f4* hb4_ = reinterpret_cast<const f4*>(bc);
                f2 accA, accB;
                accA.x = bias; accA.y = 0.f; accB.x = 0.f; accB.y = 0.f;
                REP25(DOTK)
                float d  = (accA.x + accB.x) + (accA.y + accB.y);
                float dz = __int_as_float(__builtin_amdgcn_ds_bpermute(adZ, __float_as_int(d)));
                float dn = __int_as_float(__builtin_amdgcn_ds_bpermute(adN, __float_as_int(d)));
                if (isR) {
                    float r = 1.0f / (1.0f + expf(-(g_r + d)));
                    float z = 1.0f / (1.0f + expf(-(g_z + dz)));
                    float n = tanhf(g_n + r * dn);
                    bn[q] = (1.0f - z) * n + z * hold;   // h2(k2)
                }
            } else if (wave == 5) {
                const int e = k2 + 4;          // stage a(k2+4)
                if (e < T_STEPS) {
                    while (am < e + 1) {
                        int m0 = __hip_atomic_load(af +  0, __ATOMIC_ACQUIRE, __HIP_MEMORY_SCOPE_AGENT);
                        int m1 = __hip_atomic_load(af +  8, __ATOMIC_ACQUIRE, __HIP_MEMORY_SCOPE_AGENT);
                        int m2 = __hip_atomic_load(af + 16, __ATOMIC_ACQUIRE, __HIP_MEMORY_SCOPE_AGENT);
                        int m3 = __hip_atomic_load(af + 24, __ATOMIC_ACQUIRE, __HIP_MEMORY_SCOPE_AGENT);
                        int m4 = __hip_atomic_load(af + 32, __ATOMIC_ACQUIRE, __HIP_MEMORY_SCOPE_AGENT);
                        am = min(min(min(m0, m1), min(m2, m3)), m4);
                    }
                    const float* src = ag + (size_t)e * G_DIM;
                    float* dst = ring + (e & 7) * 304;
                    dst[ln]       = __hip_atomic_load(src + ln,       __ATOMIC_RELAXED, __HIP_MEMORY_SCOPE_AGENT);
                    dst[64 + ln]  = __hip_atomic_load(src + 64 + ln,  __ATOMIC_RELAXED, __HIP_MEMORY_SCOPE_AGENT);
                    dst[128 + ln] = __hip_atomic_load(src + 128 + ln, __ATOMIC_RELAXED, __HIP_MEMORY_SCOPE_AGENT);
                    dst[192 + ln] = __hip_atomic_load(src + 192 + ln, __ATOMIC_RELAXED, __HIP_MEMORY_SCOPE_AGENT);
                    if (ln < 44)
                        dst[256 + ln] = __hip_atomic_load(src + 256 + ln, __ATOMIC_RELAXED, __HIP_MEMORY_SCOPE_AGENT);
                }
            }
            __syncthreads();
        }

        // FC epilogue: h2(T-1) written at k2 = T-1 (odd) -> bufA.
        if (tid < 64) {
            float s = 0.0f;
            for (int j = tid; j < H_DIM; j += 64) s = fmaf(fc_w[j], bufA[j], s);
            #pragma unroll
            for (int off = 32; off > 0; off >>= 1) s += __shfl_down(s, off);
            if (tid == 0) out[0] = s + fc_b[0];
        }
    }
    #undef DOTK
}

extern "C" void kernel_launch(void* const* d_in, const int* in_sizes, int n_in,
                              void* d_out, int out_size, void* d_ws, size_t ws_size,
                              hipStream_t stream) {
    const float* x     = (const float*)d_in[0];
    const float* w_ih0 = (const float*)d_in[1];
    const float* w_hh0 = (const float*)d_in[2];
    const float* b_ih0 = (const float*)d_in[3];
    const float* b_hh0 = (const float*)d_in[4];
    const float* w_ih1 = (const float*)d_in[5];
    const float* w_hh1 = (const float*)d_in[6];
    const float* b_ih1 = (const float*)d_in[7];
    const float* b_hh1 = (const float*)d_in[8];
    const float* fc_w  = (const float*)d_in[9];
    const float* fc_b  = (const float*)d_in[10];
    float* out = (float*)d_out;

    float* gi0 = (float*)d_ws;                                     // 19.66 MB
    const size_t gi0_b = (size_t)T_STEPS * G_DIM * sizeof(float);
    float* h1g = (float*)((char*)d_ws + gi0_b);                    // 6.55 MB (full history)
    float* ag  = (float*)((char*)h1g + (size_t)T_STEPS * H_DIM * sizeof(float)); // 19.66 MB
    int* flags = (int*)((char*)ag + (size_t)T_STEPS * G_DIM * sizeof(float));
    hipMemsetAsync(flags, 0, 512, stream);   // reset h1f/af each launch

    const int total = T_STEPS * G_DIM;
    gi0_kernel<<<(total + 255) / 256, 256, 0, stream>>>(x, w_ih0, b_ih0, gi0);
    gru3_kernel<<<3, 384, 0, stream>>>(gi0, w_hh0, b_hh0, w_ih1, b_ih1,
                                       w_hh1, b_hh1, fc_w, fc_b, out,
                                       h1g, ag, flags);
}

// Round 9
// 20062.952 us; speedup vs baseline: 1.6289x; 1.0634x over previous
//
#include <hip/hip_runtime.h>
#include <math.h>

#define T_STEPS 16384
#define IN_DIM  14
#define H_DIM   100
#define G_DIM   300   // 3*H

// LDS float offsets inside each 1024-float buffer.
// H2OFF=132: h1 quads hit banks 4k.., h2 quads hit banks 4k+4.. (disjoint in
// mixed waves); 132*4=528 is 16B aligned.
#define H1OFF 0
#define H2OFF 132
#define AOFF  256    // a-slab [0..300)

typedef float f2 __attribute__((ext_vector_type(2)));
typedef float f4 __attribute__((ext_vector_type(4)));

#define REP13(M) M(0) M(1) M(2) M(3) M(4) M(5) M(6) M(7) M(8) M(9) M(10) M(11) M(12)

// ---------------- Phase 0: gi0[t][j] = b_ih0[j] + sum_k x[t][k]*w_ih0[j][k] ----------------
__global__ void gi0_kernel(const float* __restrict__ x,
                           const float* __restrict__ w_ih0,
                           const float* __restrict__ b_ih0,
                           float* __restrict__ gi0) {
    int e = blockIdx.x * blockDim.x + threadIdx.x;
    if (e >= T_STEPS * G_DIM) return;
    int t = e / G_DIM;
    int j = e - t * G_DIM;
    const float* xr = x + t * IN_DIM;
    const float* wr = w_ih0 + j * IN_DIM;
    float acc = b_ih0[j];
    #pragma unroll
    for (int k = 0; k < IN_DIM; ++k) acc = fmaf(xr[k], wr[k], acc);
    gi0[e] = acc;
}

// DPP pair-exchange (quad_perm [1,0,3,2]: lane 2i <-> 2i+1), pure VALU.
__device__ __forceinline__ float pair_sum(float x) {
    int o = __builtin_amdgcn_mov_dpp(__float_as_int(x), 0xB1, 0xF, 0xF, true);
    return x + __int_as_float(o);   // commutative: both lanes get identical total
}

// ---------------- Phase 1: persistent single-workgroup sequential GRU ----------------
// ROUND 9: k-split lane pairs. Nine-round model: step time ~= 10-11 cyc per
// ds_read_b128 wave-instruction (+~300); R1's 200 broadcast reads are the
// bound; multi-CU coupling costs ~1000 cyc/step (4 failed attempts) -> stay
// single-CU and cut the DS instruction count instead.
//   (even,odd) lane pair: even holds quads 0-12 of the pair's 4 weight rows,
//   odd holds quads 12-24 (unused half-pair of quad 12 zeroed on each side).
//   h read: 13 ds_read_b128/wave (even addr = quad k, odd = quad 12+k; two
//   distinct addresses per instr = free 2-way, disjoint banks). Pair combine
//   via DPP quad_perm add (VALU pipe) -> gates fully lane-local, the two
//   ds_bpermutes of R1 are gone. DS/step: 8 waves x ~16 = ~130 instrs vs 200.
// Pair map (P = wave*32 + ln/2):
//   P<100:   l0 gate P: w_hh0 rows {P,P+100,P+200} + carried w_ih1 row P
//            (all dot h1). Even lane does the gate; odd writes a[P].
//   P<200:   l1 gate P-100: w_hh1 rows {g,g+100,g+200} (+row0 dup, CSE'd);
//            dots h2 @132. Even lane does the gate.
//   P<250:   proj: w_ih1 rows 100+4m..103+4m (dot h1); odd writes a-slab f4.
//   P>=250:  idle clones (dup m=49, never write).
// Schedule/gate math verbatim R1 (h1(it) it<T; a(it-1) 1<=it<=T; h2(it-2)
// it>=2; one barrier/iter; double-buffered LDS).
// NUMERICS NOTE: each 25-quad accumulation chain is re-associated ONCE
// (prefix quads 0-12 + suffix 13-24) -- the first deliberate departure from
// bit-exactness; expected absmax ~1e-6..1e-4.
__global__ __launch_bounds__(512, 2)
void gru_seq_kernel(const float* __restrict__ gi0,
                    const float* __restrict__ w_hh0,
                    const float* __restrict__ b_hh0,
                    const float* __restrict__ w_ih1,
                    const float* __restrict__ b_ih1,
                    const float* __restrict__ w_hh1,
                    const float* __restrict__ b_hh1,
                    const float* __restrict__ fc_w,
                    const float* __restrict__ fc_b,
                    float* __restrict__ out) {
    __shared__ __align__(16) float bufA[1024];
    __shared__ __align__(16) float bufB[1024];

    const int tid  = threadIdx.x;
    const int ln   = tid & 63;
    const int P    = tid >> 1;          // pair id 0..255 (wave*32 + ln/2)
    const bool ev  = ((ln & 1) == 0);
    const int qbase = (ln & 1) * 12;    // even: quads 0-12, odd: 12-24

    const bool isL0   = (P < 100);
    const bool isL1   = (P >= 100) && (P < 200);
    const bool isProj = (P >= 200) && (P < 250);

    const float *r0p, *r1p, *r2p, *r3p;
    float b0 = 0.f, b1 = 0.f, b2 = 0.f, b3 = 0.f;
    int g = 0, m = 0, hoff = H1OFF;
    if (isL0) {
        g = P;
        r0p = w_hh0 + (size_t)g * H_DIM;
        r1p = w_hh0 + (size_t)(g + 100) * H_DIM;
        r2p = w_hh0 + (size_t)(g + 200) * H_DIM;
        r3p = w_ih1 + (size_t)g * H_DIM;
        b0 = b_hh0[g]; b1 = b_hh0[g + 100]; b2 = b_hh0[g + 200]; b3 = b_ih1[g];
        hoff = H1OFF;
    } else if (isL1) {
        g = P - 100;
        r0p = w_hh1 + (size_t)g * H_DIM;
        r1p = w_hh1 + (size_t)(g + 100) * H_DIM;
        r2p = w_hh1 + (size_t)(g + 200) * H_DIM;
        r3p = r0p;                       // dup -> CSE, d3 discarded
        b0 = b_hh1[g]; b1 = b_hh1[g + 100]; b2 = b_hh1[g + 200]; b3 = 0.f;
        hoff = H2OFF;
    } else {
        m = P - 200; if (m > 49) m = 49; // idle pairs clone m=49
        r0p = w_ih1 + (size_t)(100 + 4 * m)     * H_DIM;
        r1p = w_ih1 + (size_t)(100 + 4 * m + 1) * H_DIM;
        r2p = w_ih1 + (size_t)(100 + 4 * m + 2) * H_DIM;
        r3p = w_ih1 + (size_t)(100 + 4 * m + 3) * H_DIM;
        b0 = b_ih1[100 + 4 * m];     b1 = b_ih1[100 + 4 * m + 1];
        b2 = b_ih1[100 + 4 * m + 2]; b3 = b_ih1[100 + 4 * m + 3];
        hoff = H1OFF;
    }

    // ---- weight half-rows: 13 quads x 4 rows, named f2 SSA values ----
    #define DECLQ(k) f2 a0_##k, b0_##k, a1_##k, b1_##k, a2_##k, b2_##k, a3_##k, b3_##k;
    REP13(DECLQ)
    #undef DECLQ
    {
        const f4* p0 = reinterpret_cast<const f4*>(r0p) + qbase;
        const f4* p1 = reinterpret_cast<const f4*>(r1p) + qbase;
        const f4* p2 = reinterpret_cast<const f4*>(r2p) + qbase;
        const f4* p3 = reinterpret_cast<const f4*>(r3p) + qbase;
        #define LOADQ(k) { f4 V; V = p0[k]; a0_##k = V.lo; b0_##k = V.hi; \
                           V = p1[k]; a1_##k = V.lo; b1_##k = V.hi; \
                           V = p2[k]; a2_##k = V.lo; b2_##k = V.hi; \
                           V = p3[k]; a3_##k = V.lo; b3_##k = V.hi; }
        REP13(LOADQ)
        #undef LOADQ
    }
    // zero the unused half of shared quad 12: even owns lo(12), odd owns hi(12)
    if (ev) { b0_12.x = 0.f; b0_12.y = 0.f; b1_12.x = 0.f; b1_12.y = 0.f;
              b2_12.x = 0.f; b2_12.y = 0.f; b3_12.x = 0.f; b3_12.y = 0.f; }
    else    { a0_0.x  = 0.f; a0_0.y  = 0.f; a1_0.x  = 0.f; a1_0.y  = 0.f;
              a2_0.x  = 0.f; a2_0.y  = 0.f; a3_0.x  = 0.f; a3_0.y  = 0.f; }

    for (int k = tid; k < 1024; k += 512) { bufA[k] = 0.0f; bufB[k] = 0.0f; }
    __syncthreads();

    // Schedule verbatim R1: l0 -> h1(it) [it<T]; proj -> a(it-1) [1<=it<=T];
    // l1 -> h2(it-2) [it>=2]. One barrier per iteration.
    for (int it = 0; it < T_STEPS + 2; ++it) {
        float* bc = (it & 1) ? bufB : bufA;
        float* bn = (it & 1) ? bufA : bufB;

        // gate-input prefetch (even lanes); dot phase covers latency
        float gr = 0.f, gz = 0.f, gn = 0.f, hold = 0.f;
        if (ev && isL0) {
            if (it < T_STEPS) {
                const float* p = gi0 + (size_t)it * G_DIM + g;
                gr = p[0]; gz = p[H_DIM]; gn = p[2 * H_DIM];
            }
            hold = bc[H1OFF + g];
        } else if (ev && isL1) {
            gr = bc[AOFF + g];
            gz = bc[AOFF + 100 + g];
            gn = bc[AOFF + 200 + g];
            hold = bc[H2OFF + g];
        }

        // Dot phase: 13 split ds_read_b128 of h; 4 rows per pair.
        const f4* hp = reinterpret_cast<const f4*>(bc + hoff) + qbase;
        f2 A0, B0, A1, B1, A2, B2, A3, B3;
        const float bsel = ev ? 1.0f : 0.0f;   // bias lives in the even (prefix) chain
        A0.x = b0 * bsel; A0.y = 0.f; B0.x = 0.f; B0.y = 0.f;
        A1.x = b1 * bsel; A1.y = 0.f; B1.x = 0.f; B1.y = 0.f;
        A2.x = b2 * bsel; A2.y = 0.f; B2.x = 0.f; B2.y = 0.f;
        A3.x = b3 * bsel; A3.y = 0.f; B3.x = 0.f; B3.y = 0.f;
        #define DOTQ(k) { f4 V = hp[k]; \
                          A0 += a0_##k * V.lo; B0 += b0_##k * V.hi; \
                          A1 += a1_##k * V.lo; B1 += b1_##k * V.hi; \
                          A2 += a2_##k * V.lo; B2 += b2_##k * V.hi; \
                          A3 += a3_##k * V.lo; B3 += b3_##k * V.hi; }
        REP13(DOTQ)
        #undef DOTQ

        // pair combine (DPP, VALU pipe): both lanes end with the full totals
        A0.x = pair_sum(A0.x); A0.y = pair_sum(A0.y); B0.x = pair_sum(B0.x); B0.y = pair_sum(B0.y);
        A1.x = pair_sum(A1.x); A1.y = pair_sum(A1.y); B1.x = pair_sum(B1.x); B1.y = pair_sum(B1.y);
        A2.x = pair_sum(A2.x); A2.y = pair_sum(A2.y); B2.x = pair_sum(B2.x); B2.y = pair_sum(B2.y);
        A3.x = pair_sum(A3.x); A3.y = pair_sum(A3.y); B3.x = pair_sum(B3.x); B3.y = pair_sum(B3.y);

        float d0 = (A0.x + B0.x) + (A0.y + B0.y);
        float d1 = (A1.x + B1.x) + (A1.y + B1.y);
        float d2 = (A2.x + B2.x) + (A2.y + B2.y);
        float d3 = (A3.x + B3.x) + (A3.y + B3.y);

        if (ev) {
            // gate math (r,z,n all lane-local now -- no bpermute)
            bool act = isL0 ? (it < T_STEPS) : (isL1 && it >= 2);
            if (act) {
                float r = 1.0f / (1.0f + expf(-(gr + d0)));
                float z = 1.0f / (1.0f + expf(-(gz + d1)));
                float n = tanhf(gn + r * d2);
                bn[hoff + g] = (1.0f - z) * n + z * hold;
            }
        } else if (it >= 1 && it <= T_STEPS) {
            if (isL0) {
                bn[AOFF + g] = d3;                       // carried w_ih1 row P
            } else if (isProj) {
                f4 w; w.x = d0; w.y = d1; w.z = d2; w.w = d3;
                reinterpret_cast<f4*>(bn + AOFF + 100)[m] = w;
            }
        }
        __syncthreads();
    }

    // FC epilogue: h2(T-1) written at it=T+1 (odd) -> bufA.
    if (tid < 64) {
        float s = 0.0f;
        for (int j = tid; j < H_DIM; j += 64) s = fmaf(fc_w[j], bufA[H2OFF + j], s);
        #pragma unroll
        for (int off = 32; off > 0; off >>= 1) s += __shfl_down(s, off);
        if (tid == 0) out[0] = s + fc_b[0];
    }
}

extern "C" void kernel_launch(void* const* d_in, const int* in_sizes, int n_in,
                              void* d_out, int out_size, void* d_ws, size_t ws_size,
                              hipStream_t stream) {
    const float* x     = (const float*)d_in[0];
    const float* w_ih0 = (const float*)d_in[1];
    const float* w_hh0 = (const float*)d_in[2];
    const float* b_ih0 = (const float*)d_in[3];
    const float* b_hh0 = (const float*)d_in[4];
    const float* w_ih1 = (const float*)d_in[5];
    const float* w_hh1 = (const float*)d_in[6];
    const float* b_ih1 = (const float*)d_in[7];
    const float* b_hh1 = (const float*)d_in[8];
    const float* fc_w  = (const float*)d_in[9];
    const float* fc_b  = (const float*)d_in[10];
    float* out = (float*)d_out;
    float* gi0 = (float*)d_ws;   // T*300 floats = 19.66 MB

    const int total = T_STEPS * G_DIM;
    gi0_kernel<<<(total + 255) / 256, 256, 0, stream>>>(x, w_ih0, b_ih0, gi0);
    gru_seq_kernel<<<1, 512, 0, stream>>>(gi0, w_hh0, b_hh0, w_ih1, b_ih1,
                                          w_hh1, b_hh1, fc_w, fc_b, out);
}